// Round 19
// baseline (488.401 us; speedup 1.0000x reference)
//
#include <hip/hip_runtime.h>
#include <cmath>

#define KSPLIT 16
#define ELL_ST 80   // max degree capacity; Poisson(16) tail beyond 80 ~ 1e-30

typedef __attribute__((ext_vector_type(8))) short short8;
typedef __attribute__((ext_vector_type(4))) float float4v;

static __device__ __forceinline__ unsigned short f2bf(float f){
  union { float f; unsigned u; } c; c.f = f;
  unsigned r = c.u + 0x7fff + ((c.u >> 16) & 1);   // RNE
  return (unsigned short)(r >> 16);
}
static __device__ __forceinline__ float u2f(unsigned u){
  union { unsigned u; float f; } c; c.u = u; return c.f;
}
static __device__ __forceinline__ float silu(float y){ return y/(1.f+__expf(-y)); }

static __device__ __forceinline__ float4 bf4_load(const unsigned short* p){
  uint2 u = *(const uint2*)p;
  float4 v;
  v.x = u2f(u.x << 16); v.y = u2f(u.x & 0xffff0000u);
  v.z = u2f(u.y << 16); v.w = u2f(u.y & 0xffff0000u);
  return v;
}
static __device__ __forceinline__ void bf4_store(unsigned short* p, float4 v){
  uint2 u;
  u.x = (unsigned)f2bf(v.x) | ((unsigned)f2bf(v.y)<<16);
  u.y = (unsigned)f2bf(v.z) | ((unsigned)f2bf(v.w)<<16);
  *(uint2*)p = u;
}

// BN affine coef {scale[128], shift[128]} from 8-slot stats into LDS (threads base..base+127)
static __device__ __forceinline__ void coef_prologue(const float* __restrict__ stats,
                                                     const float* __restrict__ gamma,
                                                     const float* __restrict__ beta,
                                                     float invM, float* lds, int tbase){
  int t = threadIdx.x - tbase;
  if(t >= 0 && t < 128){
    float s = 0.f, q = 0.f;
    #pragma unroll
    for(int k=0;k<8;k++){ s += stats[k*128+t]; q += stats[1024 + k*128+t]; }
    float m = s*invM;
    float v = q*invM - m*m;
    float sc = gamma[t]*rsqrtf(v + 1e-5f);
    lds[t] = sc;
    lds[128+t] = beta[t] - m*sc;
  }
}

// ---------------- ELL build + 3 weight transposes, one launch ----------------
__global__ void k_fill_wt(const int* __restrict__ src, const int* __restrict__ dst,
                          int* __restrict__ cursor, int* __restrict__ esrc, int E,
                          const float* __restrict__ w1a, const float* __restrict__ w1b,
                          const float* __restrict__ wp1, unsigned short* __restrict__ t1a,
                          unsigned short* __restrict__ t1b, unsigned short* __restrict__ tp1,
                          int CIN){
  int i = blockIdx.x*256 + threadIdx.x;
  if(i < E){
    int d = dst[i];
    int p = atomicAdd(&cursor[d], 1);
    if(p < ELL_ST) esrc[(size_t)d*ELL_ST + p] = src[i];
    return;
  }
  int j = i - E;
  int n1 = CIN*128, n2 = 128*128;
  if(j >= 0 && j < n1){
    int k = j >> 7, c = j & 127;
    t1a[(size_t)c*CIN + k] = f2bf(w1a[j]);
  } else if(j >= n1 && j < n1+n2){
    int jj = j - n1; int k = jj >> 7, c = jj & 127;
    t1b[(size_t)c*128 + k] = f2bf(w1b[jj]);
  } else if(j >= n1+n2 && j < n1+2*n2){
    int jj = j - n1 - n2; int k = jj >> 7, c = jj & 127;
    tp1[(size_t)c*128 + k] = f2bf(wp1[jj]);
  }
}

// ---------------- MFMA GEMM: Cb(bf16)[M,Nc] = act(A)[M,K] @ Bt[Nc,K]^T, 64x64 tile ----------
__global__ void k_gemm_mfma(const float* __restrict__ A, const float* __restrict__ A2,
                            const unsigned short* __restrict__ Bt,
                            unsigned short* __restrict__ Cb, int M, int K, int Nc,
                            const int* __restrict__ deg,
                            const float* __restrict__ stA, const float* __restrict__ gA,
                            const float* __restrict__ beA,
                            const float* __restrict__ stB, const float* __restrict__ gB,
                            const float* __restrict__ beB, float invM){
  __shared__ unsigned short Abf[64][40];
  __shared__ unsigned short Bbf[64][40];
  __shared__ float lcA[256], lcB[256];
  int tid = threadIdx.x;
  if(stA) coef_prologue(stA, gA, beA, invM, lcA, 0);
  if(stB) coef_prologue(stB, gB, beB, invM, lcB, 128);
  if(stA || stB) __syncthreads();
  int wv = tid >> 6, lane = tid & 63;
  int quad = lane >> 4, l16 = lane & 15;
  int row0 = blockIdx.y*64, col0 = blockIdx.x*64;
  int sr = tid >> 2, sk = (tid & 3)*8;
  float4v acc[4] = {};
  for(int kt=0; kt<K; kt+=32){
    const float* ap = &A[(size_t)(row0+sr)*K + kt + sk];
    float va[8];
    *(float4*)&va[0] = *(const float4*)ap;
    *(float4*)&va[4] = *(const float4*)(ap+4);
    if(stB){
      const float* bp = &A2[(size_t)(row0+sr)*K + kt + sk];
      float vb[8];
      *(float4*)&vb[0] = *(const float4*)bp;
      *(float4*)&vb[4] = *(const float4*)(bp+4);
      #pragma unroll
      for(int i=0;i<8;i++){
        int c = kt+sk+i;
        va[i] = silu(lcA[c]*va[i] + lcA[128+c]) + silu(lcB[c]*vb[i] + lcB[128+c]);
      }
    } else if(stA){
      #pragma unroll
      for(int i=0;i<8;i++){
        int c = kt+sk+i;
        va[i] = silu(lcA[c]*va[i] + lcA[128+c]);
      }
    }
    uint4 pk;
    pk.x = (unsigned)f2bf(va[0]) | ((unsigned)f2bf(va[1])<<16);
    pk.y = (unsigned)f2bf(va[2]) | ((unsigned)f2bf(va[3])<<16);
    pk.z = (unsigned)f2bf(va[4]) | ((unsigned)f2bf(va[5])<<16);
    pk.w = (unsigned)f2bf(va[6]) | ((unsigned)f2bf(va[7])<<16);
    *(uint4*)&Abf[sr][sk] = pk;
    *(uint4*)&Bbf[sr][sk] = *(const uint4*)&Bt[(size_t)(col0+sr)*K + kt + sk];
    __syncthreads();
    short8 af = *(const short8*)&Abf[wv*16 + l16][quad*8];
    #pragma unroll
    for(int t=0;t<4;t++){
      short8 bf = *(const short8*)&Bbf[t*16 + l16][quad*8];
      acc[t] = __builtin_amdgcn_mfma_f32_16x16x32_bf16(af, bf, acc[t], 0, 0, 0);
    }
    __syncthreads();
  }
  float scr[4];
  #pragma unroll
  for(int r=0;r<4;r++){
    int grow = row0 + wv*16 + quad*4 + r;
    scr[r] = rsqrtf((float)deg[grow] + 1.0f);
  }
  #pragma unroll
  for(int t=0;t<4;t++){
    #pragma unroll
    for(int r=0;r<4;r++){
      int grow = row0 + wv*16 + quad*4 + r;
      int gcol = col0 + t*16 + l16;
      Cb[(size_t)grow*Nc + gcol] = f2bf(acc[t][r]*scr[r]);
    }
  }
}

// ---------------- ELL-gather: wave/node, converged shuffle; bf16/fp32 in, bf16/fp32 out ----
template<bool DO_SOFTMAX, bool GCN, bool STATS, bool BF16IN, bool OUT16>
__global__ void k_gather(const int* __restrict__ degc, const int* __restrict__ esrc,
                         const void* __restrict__ hWs,
                         const float* __restrict__ bias, void* __restrict__ outv,
                         float* __restrict__ stats){
  __shared__ float lsum[4][128];
  __shared__ float lsq[4][128];
  const unsigned short* h16 = (const unsigned short*)hWs;
  const float* h32 = (const float*)hWs;
  int wave = threadIdx.x >> 6;
  int lane = threadIdx.x & 63;
  int bid = blockIdx.x;
  int d = ((bid & 7) << 12) | ((bid >> 3) << 2) | wave;
  int grp = lane >> 5;
  int c4 = (lane & 31)*4;
  int cntR = degc[d];                                 // raw degree (wave-uniform)
  int cnt = cntR; if(cnt > ELL_ST) cnt = ELL_ST;
  const int* row = esrc + (size_t)d*ELL_ST;

  auto loadrow = [&](int s)->float4{
    if(BF16IN) return bf4_load(&h16[(size_t)s*128 + c4]);
    else       return *(const float4*)&h32[(size_t)s*128 + c4];
  };

  float4 a0 = {0.f,0.f,0.f,0.f}, a1 = {0.f,0.f,0.f,0.f};
  float4 a2 = {0.f,0.f,0.f,0.f}, a3 = {0.f,0.f,0.f,0.f};
  if(GCN && grp == 0)
    a0 = loadrow(d);                                  // self loop
  for(int base=0; base<cnt; base+=32){
    int m = cnt - base; if(m > 32) m = 32;            // uniform
    int idx = (lane < m) ? row[base + lane] : 0;
    for(int j0 = 0; j0 < m; j0 += 8){                 // uniform bound -> converged shfl
      int jj0 = j0+grp, jj1 = j0+grp+2, jj2 = j0+grp+4, jj3 = j0+grp+6;
      int s0 = __shfl(idx, jj0 < m ? jj0 : 0);
      int s1 = __shfl(idx, jj1 < m ? jj1 : 0);
      int s2 = __shfl(idx, jj2 < m ? jj2 : 0);
      int s3 = __shfl(idx, jj3 < m ? jj3 : 0);
      if(jj0 < m){ float4 v = loadrow(s0);
        a0.x+=v.x; a0.y+=v.y; a0.z+=v.z; a0.w+=v.w; }
      if(jj1 < m){ float4 v = loadrow(s1);
        a1.x+=v.x; a1.y+=v.y; a1.z+=v.z; a1.w+=v.w; }
      if(jj2 < m){ float4 v = loadrow(s2);
        a2.x+=v.x; a2.y+=v.y; a2.z+=v.z; a2.w+=v.w; }
      if(jj3 < m){ float4 v = loadrow(s3);
        a3.x+=v.x; a3.y+=v.y; a3.z+=v.z; a3.w+=v.w; }
    }
  }
  float4 acc;
  acc.x = (a0.x+a1.x)+(a2.x+a3.x);
  acc.y = (a0.y+a1.y)+(a2.y+a3.y);
  acc.z = (a0.z+a1.z)+(a2.z+a3.z);
  acc.w = (a0.w+a1.w)+(a2.w+a3.w);
  acc.x += __shfl_xor(acc.x, 32);
  acc.y += __shfl_xor(acc.y, 32);
  acc.z += __shfl_xor(acc.z, 32);
  acc.w += __shfl_xor(acc.w, 32);
  float4 val = acc;
  if(GCN){
    float dv = rsqrtf((float)cntR + 1.0f);
    float4 bi = *(const float4*)&bias[c4];
    val.x = dv*acc.x + bi.x; val.y = dv*acc.y + bi.y;
    val.z = dv*acc.z + bi.z; val.w = dv*acc.w + bi.w;
  }
  if(DO_SOFTMAX){
    float mx = fmaxf(fmaxf(val.x,val.y), fmaxf(val.z,val.w));
    #pragma unroll
    for(int o=1;o<32;o<<=1) mx = fmaxf(mx, __shfl_xor(mx,o));
    float4 e; e.x=__expf(val.x-mx); e.y=__expf(val.y-mx);
    e.z=__expf(val.z-mx); e.w=__expf(val.w-mx);
    float s = e.x+e.y+e.z+e.w;
    #pragma unroll
    for(int o=1;o<32;o<<=1) s += __shfl_xor(s,o);
    float inv = 1.f/s;
    val.x=e.x*inv; val.y=e.y*inv; val.z=e.z*inv; val.w=e.w*inv;
  }
  if(grp == 0){
    if(OUT16) bf4_store(&((unsigned short*)outv)[(size_t)d*128 + c4], val);
    else      *(float4*)&((float*)outv)[(size_t)d*128 + c4] = val;
  }
  if(STATS){
    if(grp == 0){
      *(float4*)&lsum[wave][c4] = val;
      float4 q; q.x=val.x*val.x; q.y=val.y*val.y; q.z=val.z*val.z; q.w=val.w*val.w;
      *(float4*)&lsq[wave][c4] = q;
    }
    __syncthreads();
    int t = threadIdx.x;
    if(t < 128){
      float s = (lsum[0][t]+lsum[1][t]) + (lsum[2][t]+lsum[3][t]);
      atomicAdd(&stats[(bid & 7)*128 + t], s);
    } else {
      int c = t - 128;
      float q = (lsq[0][c]+lsq[1][c]) + (lsq[2][c]+lsq[3][c]);
      atomicAdd(&stats[1024 + (bid & 7)*128 + c], q);
    }
  }
}

// ---------------- pool split-K, output-column split for occupancy ----------------
// grid (KSPLIT, B, 4): z<2 -> fused Q (n-half = z) -> part0 ; z>=2 -> raw Q1 (n-half = z-2) -> part1.
// Each block: 128 m x 64 n output; acc[8][4] = 32 VGPR -> high occupancy.
__global__ __launch_bounds__(256, 4)
void k_pool_split(const unsigned short* __restrict__ P, const float* __restrict__ Qa0,
                  const float* __restrict__ Qb0, const unsigned short* __restrict__ Q1,
                  const float* __restrict__ stA, const float* __restrict__ gA,
                  const float* __restrict__ beA,
                  const float* __restrict__ stB, const float* __restrict__ gB,
                  const float* __restrict__ beB, float invM,
                  unsigned short* __restrict__ part0, unsigned short* __restrict__ part1,
                  int npg, int nb){
  __shared__ float Ps[2][8][132];
  __shared__ float Qs[2][8][68];
  __shared__ float lcA[256], lcB[256];
  int tid = threadIdx.x;
  int z = blockIdx.z;
  bool fused = (z < 2);                    // block-uniform
  int ncol0 = (z & 1)*64;
  if(fused){
    coef_prologue(stA, gA, beA, invM, lcA, 0);
    coef_prologue(stB, gB, beB, invM, lcB, 128);
  }
  __syncthreads();
  unsigned short* part = fused ? part0 : part1;
  int ks = blockIdx.x, b = blockIdx.y;
  int klen = npg / KSPLIT;                 // 64
  size_t base = ((size_t)b*npg + (size_t)ks*klen)*128;
  int tx = tid & 15, ty = tid >> 4;
  int rP = tid >> 5, c4s = (tid & 31)*4;   // P staging: 8 rows x 128 cols, float4/thread
  int c2 = (tid & 31)*2;                   // Q staging: 8 rows x 64 cols, float2/thread

  auto load_q2 = [&](int node)->float2{    // 2 cols at ncol0+c2 of given node row
    size_t idx = base + (size_t)node*128 + ncol0 + c2;
    float2 q;
    if(fused){
      float2 qa = *(const float2*)&Qa0[idx];
      float2 qb = *(const float2*)&Qb0[idx];
      q.x = silu(lcA[ncol0+c2+0]*qa.x+lcA[128+ncol0+c2+0]) + silu(lcB[ncol0+c2+0]*qb.x+lcB[128+ncol0+c2+0]);
      q.y = silu(lcA[ncol0+c2+1]*qa.y+lcA[128+ncol0+c2+1]) + silu(lcB[ncol0+c2+1]*qb.y+lcB[128+ncol0+c2+1]);
    } else {
      unsigned u = *(const unsigned*)&Q1[idx];
      q.x = u2f(u << 16); q.y = u2f(u & 0xffff0000u);
    }
    return q;
  };

  // stage chunk 0 into buffer 0
  {
    *(float4*)&Ps[0][rP][c4s] = bf4_load(&P[base + (size_t)rP*128 + c4s]);
    *(float2*)&Qs[0][rP][c2] = load_q2(rP);
  }
  __syncthreads();

  float acc[8][4] = {};
  int chunks = klen >> 3;                  // 8
  for(int c=0; c<chunks; c++){
    float4 pn; float2 qn;
    if(c+1 < chunks){
      int node = (c+1)*8 + rP;
      pn = bf4_load(&P[base + (size_t)node*128 + c4s]);
      qn = load_q2(node);
    }
    int cb = c & 1;
    #pragma unroll
    for(int k=0;k<8;k++){
      float4 a0 = *(const float4*)&Ps[cb][k][ty*4];
      float4 a1 = *(const float4*)&Ps[cb][k][64+ty*4];
      float4 bq = *(const float4*)&Qs[cb][k][tx*4];
      float av[8]={a0.x,a0.y,a0.z,a0.w,a1.x,a1.y,a1.z,a1.w};
      float bv[4]={bq.x,bq.y,bq.z,bq.w};
      #pragma unroll
      for(int i=0;i<8;i++)
        #pragma unroll
        for(int j=0;j<4;j++) acc[i][j] += av[i]*bv[j];
    }
    if(c+1 < chunks){
      int nbuf = (c+1) & 1;
      *(float4*)&Ps[nbuf][rP][c4s] = pn;
      *(float2*)&Qs[nbuf][rP][c2] = qn;
    }
    __syncthreads();
  }

  unsigned short* outp = part + ((size_t)(ks*nb + b)*128)*128;
  #pragma unroll
  for(int ih=0; ih<2; ih++)
    #pragma unroll
    for(int ii=0; ii<4; ii++){
      int i = ih*64 + ty*4 + ii;
      float4 v;
      v.x = acc[ih*4+ii][0];
      v.y = acc[ih*4+ii][1];
      v.z = acc[ih*4+ii][2];
      v.w = acc[ih*4+ii][3];
      bf4_store(&outp[(size_t)i*128 + ncol0 + tx*4], v);
    }
}

// reduce both bf16 partial sets; fp32 out; dinv2 from A2 row sums
__global__ void k_pool_reduce2(const unsigned short* __restrict__ p1,
                               const unsigned short* __restrict__ p2,
                               float* __restrict__ x2, float* __restrict__ A2,
                               float* __restrict__ dinv2, int total){
  int i = blockIdx.x*256 + threadIdx.x;
  int half = total >> 2;
  if(i < half){
    float4 s = bf4_load(&p1[(size_t)i*4]);
    #pragma unroll
    for(int ks=1; ks<KSPLIT; ks++){
      float4 v = bf4_load(&p1[(size_t)ks*total + (size_t)i*4]);
      s.x+=v.x; s.y+=v.y; s.z+=v.z; s.w+=v.w;
    }
    *(float4*)&x2[(size_t)i*4] = s;
  } else {
    int ia = i - half;
    float4 s = bf4_load(&p2[(size_t)ia*4]);
    #pragma unroll
    for(int ks=1; ks<KSPLIT; ks++){
      float4 v = bf4_load(&p2[(size_t)ks*total + (size_t)ia*4]);
      s.x+=v.x; s.y+=v.y; s.z+=v.z; s.w+=v.w;
    }
    *(float4*)&A2[(size_t)ia*4] = s;
    float rs = s.x+s.y+s.z+s.w;
    #pragma unroll
    for(int o=16;o>0;o>>=1) rs += __shfl_xor(rs, o);
    if((threadIdx.x & 31) == 0) dinv2[ia>>5] = rsqrtf(rs + 1.0f);
  }
}

// ---------------- fused dense layer: per (batch, 16-col slice) block ----------------
template<bool ACT>
__global__ __launch_bounds__(256, 2)
void k_dense_layer(const float* __restrict__ IN, const float* __restrict__ A2,
                   const float* __restrict__ w, const float* __restrict__ dinv2,
                   const float* __restrict__ bias,
                   const float* __restrict__ stp, const float* __restrict__ gp,
                   const float* __restrict__ bep, float invM,
                   float* __restrict__ outp, float* __restrict__ stats){
  __shared__ float ws[128][17];
  __shared__ float dWs[128][17];
  __shared__ float stg[128][17];
  __shared__ float lc[256];
  __shared__ float redS[16][17], redQ[16][17];
  int tid = threadIdx.x;
  if(ACT) coef_prologue(stp, gp, bep, invM, lc, 0);
  int b = blockIdx.y, j0 = blockIdx.x*16;
  int j = tid & 15, kg = tid >> 4;
  const float* INb = IN + (size_t)b*16384;
  const float* A2b = A2 + (size_t)b*16384;
  #pragma unroll
  for(int r=0;r<8;r++){
    int idx = r*256 + tid;
    int m = idx >> 4, jj = idx & 15;
    ws[m][jj] = w[m*128 + j0 + jj];
  }
  __syncthreads();
  float acc[8] = {};
  for(int m0=0; m0<128; m0+=16){
    #pragma unroll
    for(int r=0;r<8;r++){
      int idx = r*256 + tid;
      int k = idx >> 4, mm = idx & 15;
      float v = INb[k*128 + m0 + mm];
      if(ACT){ int c = m0+mm; v = silu(lc[c]*v + lc[128+c]); }
      stg[k][mm] = v;
    }
    __syncthreads();
    #pragma unroll
    for(int mm=0; mm<16; mm++){
      float wv = ws[m0+mm][j];
      #pragma unroll
      for(int ii=0; ii<8; ii++)
        acc[ii] += stg[kg + 16*ii][mm] * wv;
    }
    __syncthreads();
  }
  #pragma unroll
  for(int ii=0;ii<8;ii++){
    int k = kg + 16*ii;
    dWs[k][j] = acc[ii] * dinv2[b*128 + k];
  }
  __syncthreads();
  float acc2[8] = {};
  for(int k0=0;k0<128;k0+=16){
    #pragma unroll
    for(int r=0;r<8;r++){
      int idx = r*256 + tid;
      int i = idx >> 4, kk = idx & 15;
      stg[i][kk] = A2b[i*128 + k0 + kk];
    }
    __syncthreads();
    #pragma unroll
    for(int kk=0;kk<16;kk++){
      float dv = dWs[k0+kk][j];
      #pragma unroll
      for(int ii=0;ii<8;ii++)
        acc2[ii] += stg[kg + 16*ii][kk] * dv;
    }
    __syncthreads();
  }
  float ps = 0.f, pq = 0.f;
  #pragma unroll
  for(int ii=0;ii<8;ii++){
    int i = kg + 16*ii;
    int gr = b*128 + i;
    float v = dinv2[gr]*(acc2[ii] + dWs[i][j]) + bias[j0+j];
    outp[(size_t)gr*128 + j0 + j] = v;
    ps += v; pq += v*v;
  }
  redS[kg][j] = ps; redQ[kg][j] = pq;
  __syncthreads();
  if(kg == 0){
    float s = 0.f, q = 0.f;
    #pragma unroll
    for(int k=0;k<16;k++){ s += redS[k][j]; q += redQ[k][j]; }
    int slot = b & 7;
    atomicAdd(&stats[slot*128 + j0 + j], s);
    atomicAdd(&stats[1024 + slot*128 + j0 + j], q);
  }
}

// ---------------- final part 1 ----------------
__global__ void k_final_reduce(const float* __restrict__ dTa, const float* __restrict__ dTb,
                               const float* __restrict__ stA, const float* __restrict__ gA,
                               const float* __restrict__ beA,
                               const float* __restrict__ stB, const float* __restrict__ gB,
                               const float* __restrict__ beB, float invMc,
                               float* __restrict__ g, int K1n, int Cc, float inv_k2){
  __shared__ float red[256];
  __shared__ float lcA[256], lcB[256];
  coef_prologue(stA, gA, beA, invMc, lcA, 0);
  coef_prologue(stB, gB, beB, invMc, lcB, 128);
  __syncthreads();
  int b = blockIdx.y;
  int n0 = blockIdx.x*16;
  int tid = threadIdx.x;
  int c = tid & 127, rh = tid >> 7;
  const float* pa = dTa + ((size_t)b*K1n + n0)*Cc;
  const float* pb = dTb + ((size_t)b*K1n + n0)*Cc;
  float sa = lcA[c], ha = lcA[128+c], sb = lcB[c], hb = lcB[128+c];
  float acc = 0.f;
  for(int r = rh; r < 16; r += 2){
    float ya = sa*pa[(size_t)r*Cc + c] + ha;
    float yb = sb*pb[(size_t)r*Cc + c] + hb;
    acc += silu(ya) + silu(yb);
  }
  red[tid] = acc;
  __syncthreads();
  if(tid < 128)
    atomicAdd(&g[b*128 + c], (red[tid] + red[tid+128]) * inv_k2);
}

// ---------------- final part 2 ----------------
__global__ void k_final3(const float* __restrict__ g, const float* __restrict__ wl,
                         const float* __restrict__ bl, float* __restrict__ out,
                         int Cc, int OUTc, int zero_idx){
  int b = blockIdx.x;
  int t = threadIdx.x;
  __shared__ float logits[32];
  __shared__ float mred, lred;
  const float* gb = g + b*Cc;
  if(t < OUTc){
    float l = bl[t];
    for(int d=0; d<Cc; d++) l += gb[d]*wl[d*OUTc + t];
    logits[t] = l;
  }
  __syncthreads();
  if(t==0){
    float m = -1e30f;
    for(int o=0;o<OUTc;o++) m = fmaxf(m, logits[o]);
    float s = 0.f;
    for(int o=0;o<OUTc;o++) s += __expf(logits[o]-m);
    mred = m; lred = logf(s);
  }
  __syncthreads();
  if(t < OUTc) out[b*OUTc + t] = logits[t] - mred - lred;
  if(b==0 && t==0 && zero_idx >= 0) out[zero_idx] = 0.f;
}

// ---------------- launch ----------------
extern "C" void kernel_launch(void* const* d_in, const int* in_sizes, int n_in,
                              void* d_out, int out_size, void* d_ws, size_t ws_size,
                              hipStream_t stream){
  const float* x    = (const float*)d_in[0];
  const int*   ei   = (const int*)d_in[1];
  const float* w1a  = (const float*)d_in[4];
  const float* b1a  = (const float*)d_in[5];
  const float* g1a  = (const float*)d_in[6];
  const float* be1a = (const float*)d_in[7];
  const float* w1b  = (const float*)d_in[8];
  const float* b1b  = (const float*)d_in[9];
  const float* g1b  = (const float*)d_in[10];
  const float* be1b = (const float*)d_in[11];
  const float* wp1  = (const float*)d_in[12];
  const float* bp1  = (const float*)d_in[13];
  const float* w2a  = (const float*)d_in[14];
  const float* b2a  = (const float*)d_in[15];
  const float* g2a  = (const float*)d_in[16];
  const float* be2a = (const float*)d_in[17];
  const float* w2b  = (const float*)d_in[18];
  const float* b2b  = (const float*)d_in[19];
  const float* g2b  = (const float*)d_in[20];
  const float* be2b = (const float*)d_in[21];
  const float* wl   = (const float*)d_in[24];
  const float* bl   = (const float*)d_in[25];
  float* out = (float*)d_out;

  const int C_   = in_sizes[5];            // 128
  const int CIN_ = in_sizes[4]/C_;         // 64
  const int N    = in_sizes[0]/CIN_;       // 32768
  const int E    = in_sizes[1]/2;          // 524288
  const int B_   = in_sizes[3]-1;          // 32
  const int NPG_ = N/B_;                   // 1024
  const int K1_  = in_sizes[13];           // 128
  const int K2_  = in_sizes[23];           // 32
  const int OUTc = in_sizes[25];           // 10
  const int M2   = B_*K1_;                 // 4096
  const int total = M2*C_;                 // 524288

  const int* srcI = ei;
  const int* dstI = ei + E;

  float* ws = (float*)d_ws;
  size_t o = 0;
  unsigned short* bufW = (unsigned short*)(ws + o); o += (size_t)N*C_/2;   // bf16 gemm out
  float* bufA  = ws + o; o += (size_t)N*C_;   // raw 1a gather out (fp32)
  float* bufB  = ws + o; o += (size_t)N*C_;   // raw 1b gather out (fp32)
  unsigned short* bufS16 = (unsigned short*)(ws + o); o += (size_t)N*C_/2;   // s (bf16)
  unsigned short* bufT16 = (unsigned short*)(ws + o); o += (size_t)N*C_/2;   // t = A s (bf16)
  float* x2    = ws + o; o += (size_t)total;
  float* A2    = ws + o; o += (size_t)total;
  float* dinv2 = ws + o; o += (size_t)M2;
  float* st1a  = ws + o; o += 2048;
  float* st1b  = ws + o; o += 2048;
  float* stDa  = ws + o; o += 2048;
  float* stDb  = ws + o; o += 2048;
  float* gbuf  = ws + o; o += (size_t)B_*C_;   // 4096
  int* cursor  = (int*)(ws + o); o += (size_t)N;
  unsigned short* part  = (unsigned short*)(ws + o); o += (size_t)KSPLIT*total/2;  // bf16 partials
  unsigned short* part2 = (unsigned short*)(ws + o); o += (size_t)KSPLIT*total/2;
  float* dTa = ws + o; o += (size_t)total;
  float* dTb = ws + o; o += (size_t)total;
  unsigned short* wt1a = (unsigned short*)(ws + o); o += (size_t)CIN_*C_/2 + 64;
  unsigned short* wt1b = (unsigned short*)(ws + o); o += (size_t)C_*C_/2 + 64;
  unsigned short* wtp1 = (unsigned short*)(ws + o); o += (size_t)C_*C_/2 + 64;
  int* esrc    = (int*)(ws + o); o += (size_t)N*ELL_ST;
  (void)ws_size; (void)n_in;

  dim3 blk256(256);
  auto g1 = [](int n){ return dim3((unsigned)((n+255)/256)); };
  const float invN = 1.0f/N, invM2 = 1.0f/M2;

  // ---- setup: one memset (stats x4 + gbuf + cursor), ELL fill + weight transposes ----
  hipMemsetAsync(st1a, 0, (4*2048 + (size_t)B_*C_)*sizeof(float) + (size_t)N*sizeof(int), stream);
  k_fill_wt<<<g1(E + CIN_*C_ + 2*C_*C_), blk256, 0, stream>>>(srcI, dstI, cursor, esrc, E,
      w1a, w1b, wp1, wt1a, wt1b, wtp1, CIN_);

  dim3 gath((unsigned)(N/4));

  // ---- layer 1a ----
  k_gemm_mfma<<<dim3(C_/64, N/64), blk256, 0, stream>>>(x, nullptr, wt1a, bufW, N, CIN_, C_, cursor,
      nullptr, nullptr, nullptr, nullptr, nullptr, nullptr, 0.f);
  k_gather<false,true,true,true,false><<<gath, blk256, 0, stream>>>(cursor, esrc, bufW, b1a, bufA, st1a);

  // ---- layer 1b (coef1a inlined) ----
  k_gemm_mfma<<<dim3(C_/64, N/64), blk256, 0, stream>>>(bufA, nullptr, wt1b, bufW, N, C_, C_, cursor,
      st1a, g1a, be1a, nullptr, nullptr, nullptr, invN);
  k_gather<false,true,true,true,false><<<gath, blk256, 0, stream>>>(cursor, esrc, bufW, b1b, bufB, st1b);

  // ---- pool: s = softmax(gcn(h, wp1, bp1)) (bf16 out), t = A s (bf16 in/out) ----
  k_gemm_mfma<<<dim3(K1_/64, N/64), blk256, 0, stream>>>(bufA, bufB, wtp1, bufW, N, C_, K1_, cursor,
      st1a, g1a, be1a, st1b, g1b, be1b, invN);
  k_gather<true,true,false,true,true><<<gath, blk256, 0, stream>>>(cursor, esrc, bufW, bp1, bufS16, nullptr);
  k_gather<false,false,false,true,true><<<gath, blk256, 0, stream>>>(cursor, esrc, bufS16, nullptr, bufT16, nullptr);

  // x2 = s^T h (fused) ; A2 = s^T t ; dinv2 — column-split for occupancy
  k_pool_split<<<dim3(KSPLIT, B_, 4), blk256, 0, stream>>>(bufS16, bufA, bufB, bufT16,
      st1a, g1a, be1a, st1b, g1b, be1b, invN, part, part2, NPG_, B_);
  k_pool_reduce2<<<g1(total/2), blk256, 0, stream>>>(part, part2, x2, A2, dinv2, total);

  // ---- fused dense layers ----
  k_dense_layer<false><<<dim3(8, B_), blk256, 0, stream>>>(x2, A2, w2a, dinv2, b2a,
      nullptr, nullptr, nullptr, 0.f, dTa, stDa);
  k_dense_layer<true><<<dim3(8, B_), blk256, 0, stream>>>(dTa, A2, w2b, dinv2, b2b,
      stDa, g2a, be2a, invM2, dTb, stDb);

  // ---- final ----
  int zero_idx = (out_size > B_*OUTc) ? B_*OUTc : -1;
  k_final_reduce<<<dim3(K1_/16, B_), blk256, 0, stream>>>(dTa, dTb,
      stDa, g2a, be2a, stDb, g2b, be2b, invM2, gbuf, K1_, C_, 1.0f/K2_);
  k_final3<<<dim3((unsigned)B_), dim3(128), 0, stream>>>(gbuf, wl, bl, out, C_, OUTc, zero_idx);
}

// Round 20
// 392.807 us; speedup vs baseline: 1.2434x; 1.2434x over previous
//
#include <hip/hip_runtime.h>
#include <cmath>

#define KSPLIT 16
#define ELL_ST 80   // max degree capacity; Poisson(16) tail beyond 80 ~ 1e-30

typedef __attribute__((ext_vector_type(8))) short short8;
typedef __attribute__((ext_vector_type(4))) float float4v;

static __device__ __forceinline__ unsigned short f2bf(float f){
  union { float f; unsigned u; } c; c.f = f;
  unsigned r = c.u + 0x7fff + ((c.u >> 16) & 1);   // RNE
  return (unsigned short)(r >> 16);
}
static __device__ __forceinline__ float u2f(unsigned u){
  union { unsigned u; float f; } c; c.u = u; return c.f;
}
static __device__ __forceinline__ float silu(float y){ return y/(1.f+__expf(-y)); }

// BN affine coef {scale[128], shift[128]} from 8-slot stats into LDS (threads base..base+127)
static __device__ __forceinline__ void coef_prologue(const float* __restrict__ stats,
                                                     const float* __restrict__ gamma,
                                                     const float* __restrict__ beta,
                                                     float invM, float* lds, int tbase){
  int t = threadIdx.x - tbase;
  if(t >= 0 && t < 128){
    float s = 0.f, q = 0.f;
    #pragma unroll
    for(int k=0;k<8;k++){ s += stats[k*128+t]; q += stats[1024 + k*128+t]; }
    float m = s*invM;
    float v = q*invM - m*m;
    float sc = gamma[t]*rsqrtf(v + 1e-5f);
    lds[t] = sc;
    lds[128+t] = beta[t] - m*sc;
  }
}

// ---------------- ELL build ----------------
__global__ void k_fill_ell(const int* __restrict__ src, const int* __restrict__ dst,
                           int* __restrict__ cursor, int* __restrict__ esrc, int E){
  int e = blockIdx.x*256 + threadIdx.x;
  if(e<E){
    int d = dst[e];
    int p = atomicAdd(&cursor[d], 1);
    if(p < ELL_ST) esrc[(size_t)d*ELL_ST + p] = src[e];
  }
}

// ---------------- dinv + 3 weight transposes, one launch ----------------
__global__ void k_dinv_wt(const int* __restrict__ deg, float* __restrict__ dinv, int n,
                          const float* __restrict__ w1a, const float* __restrict__ w1b,
                          const float* __restrict__ wp1, unsigned short* __restrict__ t1a,
                          unsigned short* __restrict__ t1b, unsigned short* __restrict__ tp1,
                          int CIN){
  int i = blockIdx.x*256 + threadIdx.x;
  if(i < n){ dinv[i] = rsqrtf((float)deg[i] + 1.0f); }
  int j = i - n;
  int n1 = CIN*128, n2 = 128*128;
  if(j >= 0 && j < n1){
    int k = j >> 7, c = j & 127;
    t1a[(size_t)c*CIN + k] = f2bf(w1a[j]);
  } else if(j >= n1 && j < n1+n2){
    int jj = j - n1; int k = jj >> 7, c = jj & 127;
    t1b[(size_t)c*128 + k] = f2bf(w1b[jj]);
  } else if(j >= n1+n2 && j < n1+2*n2){
    int jj = j - n1 - n2; int k = jj >> 7, c = jj & 127;
    tp1[(size_t)c*128 + k] = f2bf(wp1[jj]);
  }
}

// ---------------- MFMA GEMM: Cb(bf16)[M,Nc] = act(A)[M,K] @ Bt[Nc,K]^T, 64x64 tile ----------
// stA: act = silu(affA(A)); stA+stB: act = silu(affA(A)) + silu(affB(A2)). Coef from stats prologue.
__global__ void k_gemm_mfma(const float* __restrict__ A, const float* __restrict__ A2,
                            const unsigned short* __restrict__ Bt,
                            unsigned short* __restrict__ Cb, int M, int K, int Nc,
                            const float* __restrict__ rowscale,
                            const float* __restrict__ stA, const float* __restrict__ gA,
                            const float* __restrict__ beA,
                            const float* __restrict__ stB, const float* __restrict__ gB,
                            const float* __restrict__ beB, float invM){
  __shared__ unsigned short Abf[64][40];
  __shared__ unsigned short Bbf[64][40];
  __shared__ float lcA[256], lcB[256];
  int tid = threadIdx.x;
  if(stA) coef_prologue(stA, gA, beA, invM, lcA, 0);
  if(stB) coef_prologue(stB, gB, beB, invM, lcB, 128);
  if(stA || stB) __syncthreads();
  int wv = tid >> 6, lane = tid & 63;
  int quad = lane >> 4, l16 = lane & 15;
  int row0 = blockIdx.y*64, col0 = blockIdx.x*64;
  int sr = tid >> 2, sk = (tid & 3)*8;
  float4v acc[4] = {};
  for(int kt=0; kt<K; kt+=32){
    const float* ap = &A[(size_t)(row0+sr)*K + kt + sk];
    float va[8];
    *(float4*)&va[0] = *(const float4*)ap;
    *(float4*)&va[4] = *(const float4*)(ap+4);
    if(stB){
      const float* bp = &A2[(size_t)(row0+sr)*K + kt + sk];
      float vb[8];
      *(float4*)&vb[0] = *(const float4*)bp;
      *(float4*)&vb[4] = *(const float4*)(bp+4);
      #pragma unroll
      for(int i=0;i<8;i++){
        int c = kt+sk+i;
        va[i] = silu(lcA[c]*va[i] + lcA[128+c]) + silu(lcB[c]*vb[i] + lcB[128+c]);
      }
    } else if(stA){
      #pragma unroll
      for(int i=0;i<8;i++){
        int c = kt+sk+i;
        va[i] = silu(lcA[c]*va[i] + lcA[128+c]);
      }
    }
    uint4 pk;
    pk.x = (unsigned)f2bf(va[0]) | ((unsigned)f2bf(va[1])<<16);
    pk.y = (unsigned)f2bf(va[2]) | ((unsigned)f2bf(va[3])<<16);
    pk.z = (unsigned)f2bf(va[4]) | ((unsigned)f2bf(va[5])<<16);
    pk.w = (unsigned)f2bf(va[6]) | ((unsigned)f2bf(va[7])<<16);
    *(uint4*)&Abf[sr][sk] = pk;
    *(uint4*)&Bbf[sr][sk] = *(const uint4*)&Bt[(size_t)(col0+sr)*K + kt + sk];
    __syncthreads();
    short8 af = *(const short8*)&Abf[wv*16 + l16][quad*8];
    #pragma unroll
    for(int t=0;t<4;t++){
      short8 bf = *(const short8*)&Bbf[t*16 + l16][quad*8];
      acc[t] = __builtin_amdgcn_mfma_f32_16x16x32_bf16(af, bf, acc[t], 0, 0, 0);
    }
    __syncthreads();
  }
  float scr[4];
  #pragma unroll
  for(int r=0;r<4;r++){
    int grow = row0 + wv*16 + quad*4 + r;
    scr[r] = rowscale ? rowscale[grow] : 1.f;
  }
  #pragma unroll
  for(int t=0;t<4;t++){
    #pragma unroll
    for(int r=0;r<4;r++){
      int grow = row0 + wv*16 + quad*4 + r;
      int gcol = col0 + t*16 + l16;
      Cb[(size_t)grow*Nc + gcol] = f2bf(acc[t][r]*scr[r]);
    }
  }
}

// ---------------- GEMM 64x64 tile fp32 (dense), optional inlined BN affine+SiLU on A ---------
__global__ void k_gemm64(const float* __restrict__ A, const float* __restrict__ B,
                         float* __restrict__ C, int M, int K, int Nc,
                         const float* __restrict__ rowscale,
                         const float* __restrict__ stA, const float* __restrict__ gA,
                         const float* __restrict__ beA, float invM){
  __shared__ float As[16][68];
  __shared__ float Bs[16][68];
  __shared__ float lc[256];
  int tid = threadIdx.x;
  if(stA){ coef_prologue(stA, gA, beA, invM, lc, 0); __syncthreads(); }
  int tx = tid & 15, ty = tid >> 4;
  int row0 = blockIdx.y*64, col0 = blockIdx.x*64;
  float acc[4][4] = {};
  for(int kt=0; kt<K; kt+=16){
    int ra = tid >> 2, ka = (tid & 3)*4;
    float4 va = *(const float4*)&A[(size_t)(row0+ra)*K + kt + ka];
    if(stA){
      float vv[4] = {va.x, va.y, va.z, va.w};
      #pragma unroll
      for(int i=0;i<4;i++){
        int c = kt+ka+i;
        vv[i] = silu(lc[c]*vv[i] + lc[128+c]);
      }
      va.x=vv[0]; va.y=vv[1]; va.z=vv[2]; va.w=vv[3];
    }
    As[ka+0][ra]=va.x; As[ka+1][ra]=va.y; As[ka+2][ra]=va.z; As[ka+3][ra]=va.w;
    int rb = tid >> 4, cb = (tid & 15)*4;
    *(float4*)&Bs[rb][cb] = *(const float4*)&B[(size_t)(kt+rb)*Nc + col0 + cb];
    __syncthreads();
    #pragma unroll
    for(int k=0;k<16;k++){
      float4 a = *(const float4*)&As[k][ty*4];
      float4 b = *(const float4*)&Bs[k][tx*4];
      float av[4]={a.x,a.y,a.z,a.w}, bv[4]={b.x,b.y,b.z,b.w};
      #pragma unroll
      for(int i=0;i<4;i++)
        #pragma unroll
        for(int j=0;j<4;j++) acc[i][j] += av[i]*bv[j];
    }
    __syncthreads();
  }
  #pragma unroll
  for(int i=0;i<4;i++){
    int r = row0 + ty*4 + i;
    float sc = rowscale ? rowscale[r] : 1.0f;
    float4 v; v.x=acc[i][0]*sc; v.y=acc[i][1]*sc; v.z=acc[i][2]*sc; v.w=acc[i][3]*sc;
    *(float4*)&C[(size_t)r*Nc + col0 + tx*4] = v;
  }
}

// ---------------- ELL-gather: wave/node, converged shuffle, bf16 or fp32 input ------
template<bool DO_SOFTMAX, bool GCN, bool STATS, bool BF16IN>
__global__ void k_gather(const int* __restrict__ degc, const int* __restrict__ esrc,
                         const float* __restrict__ dinv, const void* __restrict__ hWs,
                         const float* __restrict__ bias, float* __restrict__ out,
                         float* __restrict__ stats){
  __shared__ float lsum[4][128];
  __shared__ float lsq[4][128];
  const unsigned short* h16 = (const unsigned short*)hWs;
  const float* h32 = (const float*)hWs;
  int wave = threadIdx.x >> 6;
  int lane = threadIdx.x & 63;
  int bid = blockIdx.x;
  int d = ((bid & 7) << 12) | ((bid >> 3) << 2) | wave;
  int grp = lane >> 5;
  int c4 = (lane & 31)*4;
  int cnt = degc[d]; if(cnt > ELL_ST) cnt = ELL_ST;   // wave-uniform
  const int* row = esrc + (size_t)d*ELL_ST;

  auto loadrow = [&](int s)->float4{
    if(BF16IN){
      uint2 u = *(const uint2*)&h16[(size_t)s*128 + c4];
      float4 v;
      v.x = u2f(u.x << 16); v.y = u2f(u.x & 0xffff0000u);
      v.z = u2f(u.y << 16); v.w = u2f(u.y & 0xffff0000u);
      return v;
    } else {
      return *(const float4*)&h32[(size_t)s*128 + c4];
    }
  };

  float4 a0 = {0.f,0.f,0.f,0.f}, a1 = {0.f,0.f,0.f,0.f};
  float4 a2 = {0.f,0.f,0.f,0.f}, a3 = {0.f,0.f,0.f,0.f};
  if(GCN && grp == 0)
    a0 = loadrow(d);                                  // self loop
  for(int base=0; base<cnt; base+=32){
    int m = cnt - base; if(m > 32) m = 32;            // uniform
    int idx = (lane < m) ? row[base + lane] : 0;
    for(int j0 = 0; j0 < m; j0 += 8){                 // uniform bound -> converged shfl
      int jj0 = j0+grp, jj1 = j0+grp+2, jj2 = j0+grp+4, jj3 = j0+grp+6;
      int s0 = __shfl(idx, jj0 < m ? jj0 : 0);
      int s1 = __shfl(idx, jj1 < m ? jj1 : 0);
      int s2 = __shfl(idx, jj2 < m ? jj2 : 0);
      int s3 = __shfl(idx, jj3 < m ? jj3 : 0);
      if(jj0 < m){ float4 v = loadrow(s0);
        a0.x+=v.x; a0.y+=v.y; a0.z+=v.z; a0.w+=v.w; }
      if(jj1 < m){ float4 v = loadrow(s1);
        a1.x+=v.x; a1.y+=v.y; a1.z+=v.z; a1.w+=v.w; }
      if(jj2 < m){ float4 v = loadrow(s2);
        a2.x+=v.x; a2.y+=v.y; a2.z+=v.z; a2.w+=v.w; }
      if(jj3 < m){ float4 v = loadrow(s3);
        a3.x+=v.x; a3.y+=v.y; a3.z+=v.z; a3.w+=v.w; }
    }
  }
  float4 acc;
  acc.x = (a0.x+a1.x)+(a2.x+a3.x);
  acc.y = (a0.y+a1.y)+(a2.y+a3.y);
  acc.z = (a0.z+a1.z)+(a2.z+a3.z);
  acc.w = (a0.w+a1.w)+(a2.w+a3.w);
  acc.x += __shfl_xor(acc.x, 32);
  acc.y += __shfl_xor(acc.y, 32);
  acc.z += __shfl_xor(acc.z, 32);
  acc.w += __shfl_xor(acc.w, 32);
  float4 val = acc;
  if(GCN){
    float dv = dinv[d];
    float4 bi = *(const float4*)&bias[c4];
    val.x = dv*acc.x + bi.x; val.y = dv*acc.y + bi.y;
    val.z = dv*acc.z + bi.z; val.w = dv*acc.w + bi.w;
  }
  if(DO_SOFTMAX){
    float mx = fmaxf(fmaxf(val.x,val.y), fmaxf(val.z,val.w));
    #pragma unroll
    for(int o=1;o<32;o<<=1) mx = fmaxf(mx, __shfl_xor(mx,o));
    float4 e; e.x=__expf(val.x-mx); e.y=__expf(val.y-mx);
    e.z=__expf(val.z-mx); e.w=__expf(val.w-mx);
    float s = e.x+e.y+e.z+e.w;
    #pragma unroll
    for(int o=1;o<32;o<<=1) s += __shfl_xor(s,o);
    float inv = 1.f/s;
    val.x=e.x*inv; val.y=e.y*inv; val.z=e.z*inv; val.w=e.w*inv;
  }
  if(grp == 0)
    *(float4*)&out[(size_t)d*128 + c4] = val;
  if(STATS){
    if(grp == 0){
      *(float4*)&lsum[wave][c4] = val;
      float4 q; q.x=val.x*val.x; q.y=val.y*val.y; q.z=val.z*val.z; q.w=val.w*val.w;
      *(float4*)&lsq[wave][c4] = q;
    }
    __syncthreads();
    int t = threadIdx.x;
    if(t < 128){
      float s = (lsum[0][t]+lsum[1][t]) + (lsum[2][t]+lsum[3][t]);
      atomicAdd(&stats[(bid & 7)*128 + t], s);
    } else {
      int c = t - 128;
      float q = (lsq[0][c]+lsq[1][c]) + (lsq[2][c]+lsq[3][c]);
      atomicAdd(&stats[1024 + (bid & 7)*128 + c], q);
    }
  }
}

// ---------------- pool split-K: ping-pong LDS, 1 barrier/chunk, KSPLIT=16 ----
// FUSED: Q = siluA(bnA(Qa)) + siluB(bnB(Qb)) with coef from stats prologue; else Q = Qa raw.
template<bool FUSED>
__global__ __launch_bounds__(256, 2)
void k_pool_split(const float* __restrict__ P, const float* __restrict__ Qa,
                  const float* __restrict__ Qb,
                  const float* __restrict__ stA, const float* __restrict__ gA,
                  const float* __restrict__ beA,
                  const float* __restrict__ stB, const float* __restrict__ gB,
                  const float* __restrict__ beB, float invM,
                  float* __restrict__ part, int npg, int nb){
  __shared__ float Ps[2][8][132], Qs[2][8][132];
  __shared__ float lcA[256], lcB[256];
  int tid = threadIdx.x;
  if(FUSED){
    coef_prologue(stA, gA, beA, invM, lcA, 0);
    coef_prologue(stB, gB, beB, invM, lcB, 128);
    __syncthreads();
  }
  int ks = blockIdx.x, b = blockIdx.y;
  int klen = npg / KSPLIT;                 // 64
  size_t base = ((size_t)b*npg + (size_t)ks*klen)*128;
  int tx = tid & 15, ty = tid >> 4;
  int r = tid >> 5, c4s = (tid & 31)*4;
  size_t off = (size_t)r*128 + c4s;

  auto stage_q = [&](float4 qa, float4 qb)->float4{
    float4 q;
    if(FUSED){
      q.x = silu(lcA[c4s+0]*qa.x+lcA[128+c4s+0]) + silu(lcB[c4s+0]*qb.x+lcB[128+c4s+0]);
      q.y = silu(lcA[c4s+1]*qa.y+lcA[128+c4s+1]) + silu(lcB[c4s+1]*qb.y+lcB[128+c4s+1]);
      q.z = silu(lcA[c4s+2]*qa.z+lcA[128+c4s+2]) + silu(lcB[c4s+2]*qb.z+lcB[128+c4s+2]);
      q.w = silu(lcA[c4s+3]*qa.w+lcA[128+c4s+3]) + silu(lcB[c4s+3]*qb.w+lcB[128+c4s+3]);
    } else q = qa;
    return q;
  };

  {
    float4 p0 = *(const float4*)&P[base + off];
    float4 qa0 = *(const float4*)&Qa[base + off];
    float4 qb0 = FUSED ? *(const float4*)&Qb[base + off] : qa0;
    *(float4*)&Ps[0][r][c4s] = p0;
    *(float4*)&Qs[0][r][c4s] = stage_q(qa0, qb0);
  }
  __syncthreads();

  float acc[8][8] = {};
  int chunks = klen >> 3;                  // 8
  for(int c=0; c<chunks; c++){
    float4 pn, qan, qbn;
    if(c+1 < chunks){
      size_t nb2 = base + (size_t)((c+1)*8)*128 + off;
      pn  = *(const float4*)&P[nb2];
      qan = *(const float4*)&Qa[nb2];
      if(FUSED) qbn = *(const float4*)&Qb[nb2];
    }
    int cb = c & 1;
    #pragma unroll
    for(int k=0;k<8;k++){
      float4 a0 = *(const float4*)&Ps[cb][k][ty*4];
      float4 a1 = *(const float4*)&Ps[cb][k][64+ty*4];
      float4 b0 = *(const float4*)&Qs[cb][k][tx*4];
      float4 b1 = *(const float4*)&Qs[cb][k][64+tx*4];
      float av[8]={a0.x,a0.y,a0.z,a0.w,a1.x,a1.y,a1.z,a1.w};
      float bv[8]={b0.x,b0.y,b0.z,b0.w,b1.x,b1.y,b1.z,b1.w};
      #pragma unroll
      for(int i=0;i<8;i++)
        #pragma unroll
        for(int j=0;j<8;j++) acc[i][j] += av[i]*bv[j];
    }
    if(c+1 < chunks){
      int nbuf = (c+1) & 1;
      *(float4*)&Ps[nbuf][r][c4s] = pn;
      *(float4*)&Qs[nbuf][r][c4s] = stage_q(qan, FUSED ? qbn : qan);
    }
    __syncthreads();
  }

  float* outp = part + ((size_t)(ks*nb + b)*128)*128;
  #pragma unroll
  for(int ih=0; ih<2; ih++)
    #pragma unroll
    for(int ii=0; ii<4; ii++){
      int i = ih*64 + ty*4 + ii;
      #pragma unroll
      for(int jh=0; jh<2; jh++){
        float4 v;
        v.x = acc[ih*4+ii][jh*4+0];
        v.y = acc[ih*4+ii][jh*4+1];
        v.z = acc[ih*4+ii][jh*4+2];
        v.w = acc[ih*4+ii][jh*4+3];
        *(float4*)&outp[(size_t)i*128 + jh*64 + tx*4] = v;
      }
    }
}

__global__ void k_pool_reduce2(const float* __restrict__ p1, const float* __restrict__ p2,
                               float* __restrict__ x2, float* __restrict__ A2,
                               float* __restrict__ dinv2, int total){
  int i = blockIdx.x*256 + threadIdx.x;
  int half = total >> 2;
  if(i < half){
    float4 s = *(const float4*)&p1[(size_t)i*4];
    #pragma unroll
    for(int ks=1; ks<KSPLIT; ks++){
      float4 v = *(const float4*)&p1[(size_t)ks*total + (size_t)i*4];
      s.x+=v.x; s.y+=v.y; s.z+=v.z; s.w+=v.w;
    }
    *(float4*)&x2[(size_t)i*4] = s;
  } else {
    int ia = i - half;
    float4 s = *(const float4*)&p2[(size_t)ia*4];
    #pragma unroll
    for(int ks=1; ks<KSPLIT; ks++){
      float4 v = *(const float4*)&p2[(size_t)ks*total + (size_t)ia*4];
      s.x+=v.x; s.y+=v.y; s.z+=v.z; s.w+=v.w;
    }
    *(float4*)&A2[(size_t)ia*4] = s;
    float rs = s.x+s.y+s.z+s.w;
    #pragma unroll
    for(int o=16;o>0;o>>=1) rs += __shfl_xor(rs, o);
    if((threadIdx.x & 31) == 0) dinv2[ia>>5] = rsqrtf(rs + 1.0f);
  }
}

// ---------------- dense: out = dinv2[r]*(A2[b]@X + X) + bias ; + channel stats ----------------
__global__ void k_bgemm_post_stats(const float* __restrict__ A, const float* __restrict__ X,
                                   const float* __restrict__ dinv2, const float* __restrict__ bias,
                                   float* __restrict__ outp, float* __restrict__ stats){
  __shared__ float As[16][17], Xs[16][17];
  __shared__ float rs[16][17], rq[16][17];
  int b = blockIdx.z;
  int i0 = blockIdx.y*16, j0 = blockIdx.x*16;
  int tx = threadIdx.x, ty = threadIdx.y;
  const float* Ab = A + (size_t)b*16384;
  const float* Xb = X + (size_t)b*16384;
  float acc = 0.f;
  for(int k0=0;k0<128;k0+=16){
    As[ty][tx] = Ab[(i0+ty)*128 + k0+tx];
    Xs[ty][tx] = Xb[(k0+ty)*128 + j0+tx];
    __syncthreads();
    #pragma unroll
    for(int k=0;k<16;k++) acc += As[ty][k]*Xs[k][tx];
    __syncthreads();
  }
  int gr = b*128 + i0 + ty;
  float v = dinv2[gr]*(acc + Xb[(i0+ty)*128 + j0+tx]) + bias[j0+tx];
  outp[(size_t)gr*128 + j0+tx] = v;
  rs[ty][tx] = v; rq[ty][tx] = v*v;
  __syncthreads();
  if(ty == 0){
    float s = 0.f, q = 0.f;
    #pragma unroll
    for(int k=0;k<16;k++){ s += rs[k][tx]; q += rq[k][tx]; }
    int slot = b & 7;
    atomicAdd(&stats[slot*128 + j0+tx], s);
    atomicAdd(&stats[1024 + slot*128 + j0+tx], q);
  }
}

// ---------------- final part 1: g[b,c] += inv_k2 * sum_n silu(bnA(dTa)) + silu(bnB(dTb)) ----
__global__ void k_final_reduce(const float* __restrict__ dTa, const float* __restrict__ dTb,
                               const float* __restrict__ stA, const float* __restrict__ gA,
                               const float* __restrict__ beA,
                               const float* __restrict__ stB, const float* __restrict__ gB,
                               const float* __restrict__ beB, float invMc,
                               float* __restrict__ g, int K1n, int Cc, float inv_k2){
  __shared__ float red[256];
  __shared__ float lcA[256], lcB[256];
  coef_prologue(stA, gA, beA, invMc, lcA, 0);
  coef_prologue(stB, gB, beB, invMc, lcB, 128);
  __syncthreads();
  int b = blockIdx.y;
  int n0 = blockIdx.x*16;
  int tid = threadIdx.x;
  int c = tid & 127, rh = tid >> 7;   // 2 rows in flight
  const float* pa = dTa + ((size_t)b*K1n + n0)*Cc;
  const float* pb = dTb + ((size_t)b*K1n + n0)*Cc;
  float sa = lcA[c], ha = lcA[128+c], sb = lcB[c], hb = lcB[128+c];
  float acc = 0.f;
  for(int r = rh; r < 16; r += 2){
    float ya = sa*pa[(size_t)r*Cc + c] + ha;
    float yb = sb*pb[(size_t)r*Cc + c] + hb;
    acc += silu(ya) + silu(yb);
  }
  red[tid] = acc;
  __syncthreads();
  if(tid < 128)
    atomicAdd(&g[b*128 + c], (red[tid] + red[tid+128]) * inv_k2);
}

// ---------------- final part 2: logits + log-softmax from g ----------------
__global__ void k_final3(const float* __restrict__ g, const float* __restrict__ wl,
                         const float* __restrict__ bl, float* __restrict__ out,
                         int Cc, int OUTc, int zero_idx){
  int b = blockIdx.x;
  int t = threadIdx.x;   // 128
  __shared__ float logits[32];
  __shared__ float mred, lred;
  const float* gb = g + b*Cc;
  if(t < OUTc){
    float l = bl[t];
    for(int d=0; d<Cc; d++) l += gb[d]*wl[d*OUTc + t];
    logits[t] = l;
  }
  __syncthreads();
  if(t==0){
    float m = -1e30f;
    for(int o=0;o<OUTc;o++) m = fmaxf(m, logits[o]);
    float s = 0.f;
    for(int o=0;o<OUTc;o++) s += __expf(logits[o]-m);
    mred = m; lred = logf(s);
  }
  __syncthreads();
  if(t < OUTc) out[b*OUTc + t] = logits[t] - mred - lred;
  if(b==0 && t==0 && zero_idx >= 0) out[zero_idx] = 0.f;
}

// ---------------- launch ----------------
extern "C" void kernel_launch(void* const* d_in, const int* in_sizes, int n_in,
                              void* d_out, int out_size, void* d_ws, size_t ws_size,
                              hipStream_t stream){
  const float* x    = (const float*)d_in[0];
  const int*   ei   = (const int*)d_in[1];
  const float* w1a  = (const float*)d_in[4];
  const float* b1a  = (const float*)d_in[5];
  const float* g1a  = (const float*)d_in[6];
  const float* be1a = (const float*)d_in[7];
  const float* w1b  = (const float*)d_in[8];
  const float* b1b  = (const float*)d_in[9];
  const float* g1b  = (const float*)d_in[10];
  const float* be1b = (const float*)d_in[11];
  const float* wp1  = (const float*)d_in[12];
  const float* bp1  = (const float*)d_in[13];
  const float* w2a  = (const float*)d_in[14];
  const float* b2a  = (const float*)d_in[15];
  const float* g2a  = (const float*)d_in[16];
  const float* be2a = (const float*)d_in[17];
  const float* w2b  = (const float*)d_in[18];
  const float* b2b  = (const float*)d_in[19];
  const float* g2b  = (const float*)d_in[20];
  const float* be2b = (const float*)d_in[21];
  const float* wl   = (const float*)d_in[24];
  const float* bl   = (const float*)d_in[25];
  float* out = (float*)d_out;

  const int C_   = in_sizes[5];            // 128
  const int CIN_ = in_sizes[4]/C_;         // 64
  const int N    = in_sizes[0]/CIN_;       // 32768
  const int E    = in_sizes[1]/2;          // 524288
  const int B_   = in_sizes[3]-1;          // 32
  const int NPG_ = N/B_;                   // 1024
  const int K1_  = in_sizes[13];           // 128
  const int K2_  = in_sizes[23];           // 32
  const int OUTc = in_sizes[25];           // 10
  const int M2   = B_*K1_;                 // 4096
  const int total = M2*C_;                 // 524288

  const int* srcI = ei;
  const int* dstI = ei + E;

  float* ws = (float*)d_ws;
  size_t o = 0;
  float* dinv  = ws + o; o += (size_t)N;
  unsigned short* bufW = (unsigned short*)(ws + o); o += (size_t)N*C_/2;   // bf16 gemm out
  float* bufA  = ws + o; o += (size_t)N*C_;   // raw 1a gather out
  float* bufB  = ws + o; o += (size_t)N*C_;   // raw 1b gather out
  float* bufS  = ws + o; o += (size_t)N*C_;   // s
  float* bufT  = ws + o; o += (size_t)N*C_;   // t = A s
  float* x2    = ws + o; o += (size_t)total;
  float* A2    = ws + o; o += (size_t)total;
  float* dinv2 = ws + o; o += (size_t)M2;
  // zero block: 4 x 8-slot stats + gbuf + cursor — ONE memset
  float* st1a  = ws + o; o += 2048;
  float* st1b  = ws + o; o += 2048;
  float* stDa  = ws + o; o += 2048;
  float* stDb  = ws + o; o += 2048;
  float* gbuf  = ws + o; o += (size_t)B_*C_;   // 4096
  int* cursor  = (int*)(ws + o); o += (size_t)N;
  float* part  = ws + o; o += (size_t)KSPLIT*total;
  float* part2 = ws + o; o += (size_t)KSPLIT*total;
  float* dW  = part;                      // aliased after pools complete
  float* dTa = part + (size_t)total;
  float* dTb = part + 2*(size_t)total;
  unsigned short* wt1a = (unsigned short*)(ws + o); o += (size_t)CIN_*C_/2 + 64;
  unsigned short* wt1b = (unsigned short*)(ws + o); o += (size_t)C_*C_/2 + 64;
  unsigned short* wtp1 = (unsigned short*)(ws + o); o += (size_t)C_*C_/2 + 64;
  int* esrc    = (int*)(ws + o); o += (size_t)N*ELL_ST;
  (void)ws_size; (void)n_in;

  dim3 blk256(256);
  dim3 gblk(16,16);
  auto g1 = [](int n){ return dim3((unsigned)((n+255)/256)); };
  const float invN = 1.0f/N, invM2 = 1.0f/M2;

  // ---- setup: one memset (stats x4 + gbuf + cursor), ELL fill, dinv+wt ----
  hipMemsetAsync(st1a, 0, (4*2048 + (size_t)B_*C_)*sizeof(float) + (size_t)N*sizeof(int), stream);
  k_fill_ell<<<g1(E), blk256, 0, stream>>>(srcI, dstI, cursor, esrc, E);
  k_dinv_wt<<<g1(N + CIN_*C_ + 2*C_*C_), blk256, 0, stream>>>(cursor, dinv, N,
      w1a, w1b, wp1, wt1a, wt1b, wtp1, CIN_);

  dim3 gath((unsigned)(N/4));

  // ---- layer 1a ----
  k_gemm_mfma<<<dim3(C_/64, N/64), blk256, 0, stream>>>(x, nullptr, wt1a, bufW, N, CIN_, C_, dinv,
      nullptr, nullptr, nullptr, nullptr, nullptr, nullptr, 0.f);
  k_gather<false,true,true,true><<<gath, blk256, 0, stream>>>(cursor, esrc, dinv, bufW, b1a, bufA, st1a);

  // ---- layer 1b (coef1a inlined) ----
  k_gemm_mfma<<<dim3(C_/64, N/64), blk256, 0, stream>>>(bufA, nullptr, wt1b, bufW, N, C_, C_, dinv,
      st1a, g1a, be1a, nullptr, nullptr, nullptr, invN);
  k_gather<false,true,true,true><<<gath, blk256, 0, stream>>>(cursor, esrc, dinv, bufW, b1b, bufB, st1b);

  // ---- pool: s = softmax(gcn(h, wp1, bp1)), h computed on the fly ----
  k_gemm_mfma<<<dim3(K1_/64, N/64), blk256, 0, stream>>>(bufA, bufB, wtp1, bufW, N, C_, K1_, dinv,
      st1a, g1a, be1a, st1b, g1b, be1b, invN);
  k_gather<true,true,false,true><<<gath, blk256, 0, stream>>>(cursor, esrc, dinv, bufW, bp1, bufS, nullptr);
  k_gather<false,false,false,false><<<gath, blk256, 0, stream>>>(cursor, esrc, nullptr, bufS, nullptr, bufT, nullptr);

  // x2 = s^T h (fused) ; A2 = s^T t ; dinv2
  k_pool_split<true><<<dim3(KSPLIT, B_), blk256, 0, stream>>>(bufS, bufA, bufB,
      st1a, g1a, be1a, st1b, g1b, be1b, invN, part, NPG_, B_);
  k_pool_split<false><<<dim3(KSPLIT, B_), blk256, 0, stream>>>(bufS, bufT, nullptr,
      nullptr, nullptr, nullptr, nullptr, nullptr, nullptr, 0.f, part2, NPG_, B_);
  k_pool_reduce2<<<g1(total/2), blk256, 0, stream>>>(part, part2, x2, A2, dinv2, total);

  // ---- dense layer 2a ----
  k_gemm64<<<dim3(C_/64, M2/64), blk256, 0, stream>>>(x2, w2a, dW, M2, C_, C_, dinv2,
      nullptr, nullptr, nullptr, 0.f);
  k_bgemm_post_stats<<<dim3(C_/16, K1_/16, B_), gblk, 0, stream>>>(A2, dW, dinv2, b2a, dTa, stDa);

  // ---- dense layer 2b (coef2a inlined) ----
  k_gemm64<<<dim3(C_/64, M2/64), blk256, 0, stream>>>(dTa, w2b, dW, M2, C_, C_, dinv2,
      stDa, g2a, be2a, invM2);
  k_bgemm_post_stats<<<dim3(C_/16, K1_/16, B_), gblk, 0, stream>>>(A2, dW, dinv2, b2b, dTb, stDb);

  // ---- final: parallel reduce (coef2a/2b inlined) then tiny logits/log-softmax ----
  int zero_idx = (out_size > B_*OUTc) ? B_*OUTc : -1;
  k_final_reduce<<<dim3(K1_/16, B_), blk256, 0, stream>>>(dTa, dTb,
      stDa, g2a, be2a, stDb, g2b, be2b, invM2, gbuf, K1_, C_, 1.0f/K2_);
  k_final3<<<dim3((unsigned)B_), dim3(128), 0, stream>>>(gbuf, wl, bl, out, C_, OUTc, zero_idx);
}